// Round 13
// baseline (727.866 us; speedup 1.0000x reference)
//
#include <hip/hip_runtime.h>
#include <stdint.h>

typedef unsigned short u16;
typedef __attribute__((ext_vector_type(4))) float f32x4;
typedef __attribute__((ext_vector_type(8))) short short8;
typedef __attribute__((ext_vector_type(8))) unsigned short u16x8;

static constexpr int Bq = 8192;     // batch
static constexpr int Dq = 1024;     // feature dim (K)
static constexpr int Eq = 32;       // experts
static constexpr int Aq = 128;      // actions
static constexpr int NSTRAT = 4096; // E*A strat columns = GEMM N

__device__ inline u16 f32_to_bf16_rne(float f) {
    uint32_t u = __float_as_uint(f);
    uint32_t r = 0x7fffu + ((u >> 16) & 1u);
    return (u16)((u + r) >> 16);
}
__device__ inline float bf16_to_f32(u16 h) {
    return __uint_as_float(((uint32_t)h) << 16);
}
__device__ inline void gload_lds16(const u16* g, u16* l) {
    __builtin_amdgcn_global_load_lds(
        (const __attribute__((address_space(1))) void*)g,
        (__attribute__((address_space(3))) void*)l, 16, 0, 0);
}
__device__ inline short8 cvt8(const float* p) {
    f32x4 a = *(const f32x4*)p;
    f32x4 b = *(const f32x4*)(p + 4);
    short8 o;
    o[0] = (short)f32_to_bf16_rne(a[0]); o[1] = (short)f32_to_bf16_rne(a[1]);
    o[2] = (short)f32_to_bf16_rne(a[2]); o[3] = (short)f32_to_bf16_rne(a[3]);
    o[4] = (short)f32_to_bf16_rne(b[0]); o[5] = (short)f32_to_bf16_rne(b[1]);
    o[6] = (short)f32_to_bf16_rne(b[2]); o[7] = (short)f32_to_bf16_rne(b[3]);
    return o;
}
// DPP 16-lane sum (gfx9 "row" = 16 lanes): all lanes end with the row-sum. VALU-only.
template <int CTRL>
__device__ inline float dppadd(float v) {
    int t = __builtin_amdgcn_update_dpp(0, __float_as_int(v), CTRL, 0xf, 0xf, false);
    return v + __int_as_float(t);
}
__device__ inline float red16(float v) {
    v = dppadd<0xb1>(v);   // quad_perm [1,0,3,2]  (xor 1)
    v = dppadd<0x4e>(v);   // quad_perm [2,3,0,1]  (xor 2)
    v = dppadd<0x124>(v);  // row_ror:4
    v = dppadd<0x128>(v);  // row_ror:8
    return v;
}

#define MF(a, b, c) __builtin_amdgcn_mfma_f32_16x16x32_bf16(a, b, c, 0, 0, 0)

// ------- fused convert to bf16: x[8192x1024] then PERMUTED W_strat.
// Wb row col' = a*32 + e  <-  W_strat[e][a][:]   (expert axis innermost in N)
__global__ __launch_bounds__(256) void cvt_fused(const float* __restrict__ x,
                                                 const float* __restrict__ Ws,
                                                 u16* __restrict__ xb) {
    size_t i = ((size_t)blockIdx.x * 256 + threadIdx.x) * 8;
    const size_t XN = (size_t)Bq * Dq;
    const float* src;
    if (i < XN) {
        src = x + i;
    } else {
        size_t j = i - XN;
        int rp = (int)(j >> 10);            // col' = a*32 + e
        int e = rp & 31;
        int a = rp >> 5;
        src = Ws + ((size_t)((e << 7) + a) << 10) + (j & 1023);
    }
    short8 o = cvt8(src);
    *(short8*)(xb + i) = o;
}

// ============ gating: logits GEMV (MFMA) + gumbel-softmax -> wT[e][row] (transposed) ============
__global__ __launch_bounds__(512) void logits_kernel(const u16* __restrict__ xb,
                                                     const float* __restrict__ W_att,
                                                     const float* __restrict__ b_att,
                                                     const float* __restrict__ abias,
                                                     const float* __restrict__ gu,
                                                     float* __restrict__ wT) {
    __shared__ __align__(16) u16 Wa[32][1032]; // pad 8 u16: row stride 2064 B

    const int tid = threadIdx.x;
    const int lane = tid & 63;
    const int wv = tid >> 6;
    const int fr = lane & 15;
    const int fq = lane >> 4;
    const int m0 = blockIdx.x * 128;

    // stage W_att f32 -> bf16 LDS
    {
        const int row = tid >> 4;            // 0..31
        const int col0 = (tid & 15) * 64;
        const float* src = W_att + (size_t)row * 1024 + col0;
        u16* dst = &Wa[row][col0];
#pragma unroll
        for (int it = 0; it < 8; ++it) {
            short8 o = cvt8(src + it * 8);
            *(short8*)(dst + it * 8) = o;
        }
    }
    __syncthreads();

    f32x4 acc0 = {}, acc1 = {};
    const u16* xrow = xb + (size_t)(m0 + wv * 16 + fr) * 1024 + fq * 8;
#pragma unroll 4
    for (int k0 = 0; k0 < 1024; k0 += 32) {
        short8 a0 = *(const short8*)(xrow + k0);
        short8 b0 = *(const short8*)(&Wa[fr][k0 + fq * 8]);
        short8 b1 = *(const short8*)(&Wa[16 + fr][k0 + fq * 8]);
        acc0 = MF(a0, b0, acc0);
        acc1 = MF(a0, b1, acc1);
    }

    const float bba0 = b_att[fr] + abias[fr];
    const float bba1 = b_att[16 + fr] + abias[16 + fr];
#pragma unroll
    for (int q = 0; q < 4; ++q) {
        const int row = m0 + wv * 16 + fq * 4 + q;
        float u0 = gu[(size_t)row * 32 + fr];
        float u1 = gu[(size_t)row * 32 + 16 + fr];
        // accurate logf: hw __logf near u->1 loses all precision in -log(u)
        float g0 = -logf(-logf(u0 + 1e-10f) + 1e-10f);
        float g1 = -logf(-logf(u1 + 1e-10f) + 1e-10f);
        float z0 = acc0[q] + bba0 + g0;
        float z1 = acc1[q] + bba1 + g1;
        float mx = fmaxf(z0, z1);
#pragma unroll
        for (int s = 1; s < 16; s <<= 1) mx = fmaxf(mx, __shfl_xor(mx, s));
        float p0 = __expf(z0 - mx);
        float p1 = __expf(z1 - mx);
        float sm = p0 + p1;
#pragma unroll
        for (int s = 1; s < 16; s <<= 1) sm += __shfl_xor(sm, s);
        float inv = 1.0f / sm;
        wT[(size_t)fr * Bq + row] = p0 * inv;
        wT[(size_t)(16 + fr) * Bq + row] = p1 * inv;
    }
}

// ================= 256x256 GEMM, BK=32 / 64KiB LDS / 2 blocks per CU =================
// Same 8-phase R2-ledger slot pattern + R12 trailing-barrier-only; guards VMCNT(1).
// 64B row stride => naturally even bank rotation; NO LDS swizzle anywhere (derived:
// byte = fr*64 + fq*16 -> start banks {0,4,...,28}, 8 lanes each = even b128 floor).
#define FBAR do { asm volatile("" ::: "memory"); __builtin_amdgcn_s_barrier(); asm volatile("" ::: "memory"); } while (0)
#define LGKM0 asm volatile("s_waitcnt lgkmcnt(0)" ::: "memory")
#define VMCNT(n) asm volatile("s_waitcnt vmcnt(" #n ")" ::: "memory")
#define SB __builtin_amdgcn_sched_barrier(0)
#define PRIO1 __builtin_amdgcn_s_setprio(1)
#define PRIO0 __builtin_amdgcn_s_setprio(0)

// LDS: [buf][A=0/B=1][256 rows x 32 k] u16 = 64 KiB total.
#define STAGE_A(buf, h, kt) \
    gload_lds16(agA + (size_t)((h)*128) * 1024 + (size_t)(kt) * 32, (u16*)&lds[buf][0][(h)*4096 + tid * 8])
#define STAGE_B(buf, h, kt) \
    gload_lds16(agB + (size_t)((h)*128) * 1024 + (size_t)(kt) * 32, (u16*)&lds[buf][1][(h)*4096 + tid * 8])

#define LDA4(DST, ABASE, mq) do { \
    DST[0] = *(const short8*)((ABASE) + (mq)*2048 + 0*512 + aoff); \
    DST[1] = *(const short8*)((ABASE) + (mq)*2048 + 1*512 + aoff); \
    DST[2] = *(const short8*)((ABASE) + (mq)*2048 + 2*512 + aoff); \
    DST[3] = *(const short8*)((ABASE) + (mq)*2048 + 3*512 + aoff); \
} while (0)
#define LDB2(DST, BBASE, nq) do { \
    DST[0] = *(const short8*)((BBASE) + (nq)*1024 + 0*512 + aoff); \
    DST[1] = *(const short8*)((BBASE) + (nq)*1024 + 1*512 + aoff); \
} while (0)

#define QUAD8(mq, nq, AS, BS) do { \
    acc[(mq)*4+0][(nq)*2+0] = MF(AS[0], BS[0], acc[(mq)*4+0][(nq)*2+0]); \
    acc[(mq)*4+0][(nq)*2+1] = MF(AS[0], BS[1], acc[(mq)*4+0][(nq)*2+1]); \
    acc[(mq)*4+1][(nq)*2+0] = MF(AS[1], BS[0], acc[(mq)*4+1][(nq)*2+0]); \
    acc[(mq)*4+1][(nq)*2+1] = MF(AS[1], BS[1], acc[(mq)*4+1][(nq)*2+1]); \
    acc[(mq)*4+2][(nq)*2+0] = MF(AS[2], BS[0], acc[(mq)*4+2][(nq)*2+0]); \
    acc[(mq)*4+2][(nq)*2+1] = MF(AS[2], BS[1], acc[(mq)*4+2][(nq)*2+1]); \
    acc[(mq)*4+3][(nq)*2+0] = MF(AS[3], BS[0], acc[(mq)*4+3][(nq)*2+0]); \
    acc[(mq)*4+3][(nq)*2+1] = MF(AS[3], BS[1], acc[(mq)*4+3][(nq)*2+1]); \
} while (0)

// Stage slots (per GITER, 2 K-tiles t/buf0, t+1/buf1):
//   P1: A(t+1)h0->buf1A  P2: A(t+1)h1  P3: B(t+2)h0->buf0B  P4: B(t+2)h1
//   P5: A(t+2)h0->buf0A  P6: A(t+2)h1  P7: B(t+3)h0->buf1B  P8: B(t+3)h1
// Guards: end-P3 VMCNT(1) (forces B(t+1)+A(t+1)); end-P7 VMCNT(1) (forces B(t+2)+A(t+2)).
// Overwrite safety (trailing-bar skew <1 phase, audited): every stage's region had its
// last ds_read >=1 barrier earlier.
#define GITER(t, TAIL) do { \
    /* ph1 */ \
    LDB2(Bs0, Bbase0, 0); \
    STAGE_A(1, 0, (t) + 1); \
    SB; LGKM0; SB; \
    PRIO1; QUAD8(0, 0, As0, Bs0); PRIO0; SB; FBAR; \
    /* ph2 */ \
    LDB2(Bs1, Bbase0, 1); \
    STAGE_A(1, 1, (t) + 1); \
    SB; LGKM0; SB; \
    PRIO1; QUAD8(0, 1, As0, Bs1); PRIO0; SB; FBAR; \
    /* ph3 */ \
    LDA4(As1, Abase0, 1); \
    if (!(TAIL)) STAGE_B(0, 0, (t) + 2); \
    SB; LGKM0; SB; \
    PRIO1; QUAD8(1, 1, As1, Bs1); PRIO0; SB; \
    if (TAIL) { VMCNT(0); } else { VMCNT(1); } \
    FBAR; \
    /* ph4 */ \
    LDA4(As0, Abase1, 0); \
    if (!(TAIL)) STAGE_B(0, 1, (t) + 2); \
    SB; LGKM0; SB; \
    PRIO1; QUAD8(1, 0, As1, Bs0); PRIO0; SB; FBAR; \
    /* ph5 */ \
    LDB2(Bs0, Bbase1, 0); \
    if (!(TAIL)) STAGE_A(0, 0, (t) + 2); \
    SB; LGKM0; SB; \
    PRIO1; QUAD8(0, 0, As0, Bs0); PRIO0; SB; FBAR; \
    /* ph6 */ \
    LDB2(Bs1, Bbase1, 1); \
    if (!(TAIL)) STAGE_A(0, 1, (t) + 2); \
    SB; LGKM0; SB; \
    PRIO1; QUAD8(0, 1, As0, Bs1); PRIO0; SB; FBAR; \
    /* ph7 */ \
    LDA4(As1, Abase1, 1); \
    if (!(TAIL)) STAGE_B(1, 0, (t) + 3); \
    SB; LGKM0; SB; \
    PRIO1; QUAD8(1, 1, As1, Bs1); PRIO0; SB; \
    if (!(TAIL)) { VMCNT(1); } \
    FBAR; \
    /* ph8 */ \
    if (!(TAIL)) { LDA4(As0, Abase0, 0); STAGE_B(1, 1, (t) + 3); } \
    SB; LGKM0; SB; \
    PRIO1; QUAD8(1, 0, As1, Bs0); PRIO0; SB; FBAR; \
} while (0)

__global__ __launch_bounds__(512, 4) void gemm256(const u16* __restrict__ Abuf,
                                                  const u16* __restrict__ Bbuf,
                                                  const float* __restrict__ wT,
                                                  const float* __restrict__ b_strat,
                                                  float* __restrict__ out) {
    __shared__ __align__(16) u16 lds[2][2][8192]; // 64 KiB -> 2 blocks/CU

    const int tid = threadIdx.x;
    const int lane = tid & 63;
    const int wv = tid >> 6;
    const int wr = wv >> 2;      // 0..1 (M)
    const int wc = wv & 3;       // 0..3 (N)
    const int fr = lane & 15;
    const int fq = lane >> 4;

    // XCD-aware bijective mapping, m-fastest within XCD (R9): FETCH 76.5->52.4 MB measured.
    const int bid = blockIdx.x;
    const int xcd = bid & 7;
    const int k = bid >> 3;                  // 0..63
    const int m0 = (xcd * 4 + (k & 3)) * 256;
    const int n0 = (k >> 2) * 256;

    // staging: plain linear (no swizzle needed at 64B row stride)
    const int s_r = tid >> 2;                // row within 128-half
    const int s_c = (tid & 3) * 8;           // k-chunk
    const u16* agA = Abuf + (size_t)(m0 + s_r) * 1024 + s_c;
    const u16* agB = Bbuf + (size_t)(n0 + s_r) * 1024 + s_c;

    // frag-read offset (u16 units): row stride 32, chunk fq
    const int aoff = fr * 32 + fq * 8;

    const u16* Abase0 = (const u16*)&lds[0][0][wr * 4096];
    const u16* Abase1 = (const u16*)&lds[1][0][wr * 4096];
    const u16* Bbase0 = (const u16*)&lds[0][1][wc * 2048];
    const u16* Bbase1 = (const u16*)&lds[1][1][wc * 2048];

    f32x4 acc[8][4] = {};
    short8 As0[4], As1[4], Bs0[2], Bs1[2];

    // prologue: tile0 full into buf0, B(1) into buf1; VMCNT(2) forces tile0 (B(1) in flight)
    STAGE_A(0, 0, 0); STAGE_A(0, 1, 0); STAGE_B(0, 0, 0); STAGE_B(0, 1, 0);
    STAGE_B(1, 0, 1); STAGE_B(1, 1, 1);
    SB; VMCNT(2); FBAR;
    LDA4(As0, Abase0, 0);

#pragma unroll 1
    for (int t = 0; t < 30; t += 2) { GITER(t, 0); }
    GITER(30, 1);

    // ---- block-local weighted combine epilogue (DPP row-sum + vectorized wT loads) ----
    // C layout: row = crow + im*16 + q, col' = n0 + wc*64 + jn*16 + fr  (m89-verified)
    // col' = a*32 + e  ->  e = (jn&1)*16 + fr,  a = (n0>>5) + wc*2 + (jn>>1)
    const int crow = m0 + wr * 128 + fq * 4;
    const int a0 = (n0 >> 5) + wc * 2;
    const float bs00 = b_strat[fr * 128 + a0];
    const float bs10 = b_strat[(16 + fr) * 128 + a0];
    const float bs01 = b_strat[fr * 128 + a0 + 1];
    const float bs11 = b_strat[(16 + fr) * 128 + a0 + 1];
    const float* wt0 = wT + (size_t)fr * Bq;
    const float* wt1 = wT + (size_t)(16 + fr) * Bq;
#pragma unroll
    for (int im = 0; im < 8; ++im) {
        f32x4 w0 = *(const f32x4*)(wt0 + crow + im * 16);   // w[fr][row] for q=0..3
        f32x4 w1 = *(const f32x4*)(wt1 + crow + im * 16);
#pragma unroll
        for (int q = 0; q < 4; ++q) {
            float v0 = w0[q] * (acc[im][0][q] + bs00) + w1[q] * (acc[im][1][q] + bs10);
            float v1 = w0[q] * (acc[im][2][q] + bs01) + w1[q] * (acc[im][3][q] + bs11);
            v0 = red16(v0);
            v1 = red16(v1);
            if (fr == 0) {
                const int row = crow + im * 16 + q;
                out[(size_t)row * 128 + a0] = v0;
                out[(size_t)row * 128 + a0 + 1] = v1;
            }
        }
    }
}

extern "C" void kernel_launch(void* const* d_in, const int* in_sizes, int n_in,
                              void* d_out, int out_size, void* d_ws, size_t ws_size,
                              hipStream_t stream) {
    (void)in_sizes; (void)n_in; (void)out_size; (void)ws_size;
    const float* x       = (const float*)d_in[0];
    const float* W_att   = (const float*)d_in[1];
    const float* b_att   = (const float*)d_in[2];
    const float* abias   = (const float*)d_in[3];
    const float* W_strat = (const float*)d_in[4];
    const float* b_strat = (const float*)d_in[5];
    const float* gu      = (const float*)d_in[6];
    float* out = (float*)d_out;

    // ws layout: xb [8192][1024] | Wb [4096][1024] (permuted, contiguous bf16) | wT [32][8192] f32
    u16* xb = (u16*)d_ws;
    u16* Wb = xb + (size_t)Bq * Dq;
    float* wT = (float*)(Wb + (size_t)NSTRAT * Dq);

    cvt_fused<<<(Bq * Dq + NSTRAT * Dq) / (256 * 8), 256, 0, stream>>>(x, W_strat, xb);

    logits_kernel<<<Bq / 128, 512, 0, stream>>>(xb, W_att, b_att, abias, gu, wT);

    gemm256<<<512, 512, 0, stream>>>(xb, Wb, wT, b_strat, out);
}

// Round 14
// 91.695 us; speedup vs baseline: 7.9379x; 7.9379x over previous
//
#include <hip/hip_runtime.h>
#include <stdint.h>

typedef unsigned short u16;
typedef __attribute__((ext_vector_type(4))) float f32x4;
typedef __attribute__((ext_vector_type(8))) short short8;
typedef __attribute__((ext_vector_type(8))) unsigned short u16x8;

static constexpr int Bq = 8192;     // batch
static constexpr int Dq = 1024;     // feature dim (K)
static constexpr int Eq = 32;       // experts
static constexpr int Aq = 128;      // actions
static constexpr int NSTRAT = 4096; // E*A strat columns = GEMM N

__device__ inline u16 f32_to_bf16_rne(float f) {
    uint32_t u = __float_as_uint(f);
    uint32_t r = 0x7fffu + ((u >> 16) & 1u);
    return (u16)((u + r) >> 16);
}
__device__ inline float bf16_to_f32(u16 h) {
    return __uint_as_float(((uint32_t)h) << 16);
}
__device__ inline void gload_lds16(const u16* g, u16* l) {
    __builtin_amdgcn_global_load_lds(
        (const __attribute__((address_space(1))) void*)g,
        (__attribute__((address_space(3))) void*)l, 16, 0, 0);
}
__device__ inline short8 cvt8(const float* p) {
    f32x4 a = *(const f32x4*)p;
    f32x4 b = *(const f32x4*)(p + 4);
    short8 o;
    o[0] = (short)f32_to_bf16_rne(a[0]); o[1] = (short)f32_to_bf16_rne(a[1]);
    o[2] = (short)f32_to_bf16_rne(a[2]); o[3] = (short)f32_to_bf16_rne(a[3]);
    o[4] = (short)f32_to_bf16_rne(b[0]); o[5] = (short)f32_to_bf16_rne(b[1]);
    o[6] = (short)f32_to_bf16_rne(b[2]); o[7] = (short)f32_to_bf16_rne(b[3]);
    return o;
}
// DPP 16-lane sum (gfx9 "row" = 16 lanes): all lanes end with the row-sum. VALU-only.
template <int CTRL>
__device__ inline float dppadd(float v) {
    int t = __builtin_amdgcn_update_dpp(0, __float_as_int(v), CTRL, 0xf, 0xf, false);
    return v + __int_as_float(t);
}
__device__ inline float red16(float v) {
    v = dppadd<0xb1>(v);   // quad_perm [1,0,3,2]  (xor 1)
    v = dppadd<0x4e>(v);   // quad_perm [2,3,0,1]  (xor 2)
    v = dppadd<0x124>(v);  // row_ror:4
    v = dppadd<0x128>(v);  // row_ror:8
    return v;
}

#define MF(a, b, c) __builtin_amdgcn_mfma_f32_16x16x32_bf16(a, b, c, 0, 0, 0)

// ------- fused convert to bf16: x[8192x1024] then PERMUTED W_strat.
// Wb row col' = a*32 + e  <-  W_strat[e][a][:]   (expert axis innermost in N)
__global__ __launch_bounds__(256) void cvt_fused(const float* __restrict__ x,
                                                 const float* __restrict__ Ws,
                                                 u16* __restrict__ xb) {
    size_t i = ((size_t)blockIdx.x * 256 + threadIdx.x) * 8;
    const size_t XN = (size_t)Bq * Dq;
    const float* src;
    if (i < XN) {
        src = x + i;
    } else {
        size_t j = i - XN;
        int rp = (int)(j >> 10);            // col' = a*32 + e
        int e = rp & 31;
        int a = rp >> 5;
        src = Ws + ((size_t)((e << 7) + a) << 10) + (j & 1023);
    }
    short8 o = cvt8(src);
    *(short8*)(xb + i) = o;
}

// ============ gating: logits GEMV (MFMA) + gumbel-softmax -> wT[e][row] (transposed) ============
__global__ __launch_bounds__(512) void logits_kernel(const u16* __restrict__ xb,
                                                     const float* __restrict__ W_att,
                                                     const float* __restrict__ b_att,
                                                     const float* __restrict__ abias,
                                                     const float* __restrict__ gu,
                                                     float* __restrict__ wT) {
    __shared__ __align__(16) u16 Wa[32][1032]; // pad 8 u16: row stride 2064 B

    const int tid = threadIdx.x;
    const int lane = tid & 63;
    const int wv = tid >> 6;
    const int fr = lane & 15;
    const int fq = lane >> 4;
    const int m0 = blockIdx.x * 128;

    // stage W_att f32 -> bf16 LDS
    {
        const int row = tid >> 4;            // 0..31
        const int col0 = (tid & 15) * 64;
        const float* src = W_att + (size_t)row * 1024 + col0;
        u16* dst = &Wa[row][col0];
#pragma unroll
        for (int it = 0; it < 8; ++it) {
            short8 o = cvt8(src + it * 8);
            *(short8*)(dst + it * 8) = o;
        }
    }
    __syncthreads();

    f32x4 acc0 = {}, acc1 = {};
    const u16* xrow = xb + (size_t)(m0 + wv * 16 + fr) * 1024 + fq * 8;
#pragma unroll 4
    for (int k0 = 0; k0 < 1024; k0 += 32) {
        short8 a0 = *(const short8*)(xrow + k0);
        short8 b0 = *(const short8*)(&Wa[fr][k0 + fq * 8]);
        short8 b1 = *(const short8*)(&Wa[16 + fr][k0 + fq * 8]);
        acc0 = MF(a0, b0, acc0);
        acc1 = MF(a0, b1, acc1);
    }

    const float bba0 = b_att[fr] + abias[fr];
    const float bba1 = b_att[16 + fr] + abias[16 + fr];
#pragma unroll
    for (int q = 0; q < 4; ++q) {
        const int row = m0 + wv * 16 + fq * 4 + q;
        float u0 = gu[(size_t)row * 32 + fr];
        float u1 = gu[(size_t)row * 32 + 16 + fr];
        // accurate logf: hw __logf near u->1 loses all precision in -log(u)
        float g0 = -logf(-logf(u0 + 1e-10f) + 1e-10f);
        float g1 = -logf(-logf(u1 + 1e-10f) + 1e-10f);
        float z0 = acc0[q] + bba0 + g0;
        float z1 = acc1[q] + bba1 + g1;
        float mx = fmaxf(z0, z1);
#pragma unroll
        for (int s = 1; s < 16; s <<= 1) mx = fmaxf(mx, __shfl_xor(mx, s));
        float p0 = __expf(z0 - mx);
        float p1 = __expf(z1 - mx);
        float sm = p0 + p1;
#pragma unroll
        for (int s = 1; s < 16; s <<= 1) sm += __shfl_xor(sm, s);
        float inv = 1.0f / sm;
        wT[(size_t)fr * Bq + row] = p0 * inv;
        wT[(size_t)(16 + fr) * Bq + row] = p1 * inv;
    }
}

// ================= 256x256 8-phase GEMM, trailing-barrier-only phases, fused combine epilogue =================
#define FBAR do { asm volatile("" ::: "memory"); __builtin_amdgcn_s_barrier(); asm volatile("" ::: "memory"); } while (0)
#define LGKM0 asm volatile("s_waitcnt lgkmcnt(0)" ::: "memory")
#define VMCNT(n) asm volatile("s_waitcnt vmcnt(" #n ")" ::: "memory")
#define SB __builtin_amdgcn_sched_barrier(0)
#define PRIO1 __builtin_amdgcn_s_setprio(1)
#define PRIO0 __builtin_amdgcn_s_setprio(0)

// LDS: 2 buffers (K-tile parity) x 4 regions (A-h0, A-h1, B-h0, B-h1) x 16KB.
// Swizzle: within a region (row stride 128B), byte ^= (row&7)<<4 (elem ^= (row&7)<<3).
// Staged linearly via pre-swizzled global source (rule #21).

#define STAGE_A(buf, h, kt) do { \
    gload_lds16(agA + (size_t)((h)*128) * 1024 + (size_t)(kt) * 64, (u16*)&lds[buf][h][tid * 8]); \
    gload_lds16(agA + (size_t)((h)*128 + 64) * 1024 + (size_t)(kt) * 64, (u16*)&lds[buf][h][4096 + tid * 8]); \
} while (0)
#define STAGE_B(buf, h, kt) do { \
    gload_lds16(agB + (size_t)((h)*128) * 1024 + (size_t)(kt) * 64, (u16*)&lds[buf][2 + (h)][tid * 8]); \
    gload_lds16(agB + (size_t)((h)*128 + 64) * 1024 + (size_t)(kt) * 64, (u16*)&lds[buf][2 + (h)][4096 + tid * 8]); \
} while (0)

#define LDA8(DST, ABASE, mq) do { \
    DST[0] = *(const short8*)((ABASE) + (mq)*4096 + 0*1024 + aoff0); \
    DST[1] = *(const short8*)((ABASE) + (mq)*4096 + 0*1024 + aoff1); \
    DST[2] = *(const short8*)((ABASE) + (mq)*4096 + 1*1024 + aoff0); \
    DST[3] = *(const short8*)((ABASE) + (mq)*4096 + 1*1024 + aoff1); \
    DST[4] = *(const short8*)((ABASE) + (mq)*4096 + 2*1024 + aoff0); \
    DST[5] = *(const short8*)((ABASE) + (mq)*4096 + 2*1024 + aoff1); \
    DST[6] = *(const short8*)((ABASE) + (mq)*4096 + 3*1024 + aoff0); \
    DST[7] = *(const short8*)((ABASE) + (mq)*4096 + 3*1024 + aoff1); \
} while (0)
#define LDB4(DST, BBASE, nq) do { \
    DST[0] = *(const short8*)((BBASE) + (nq)*2048 + 0*1024 + boff0); \
    DST[1] = *(const short8*)((BBASE) + (nq)*2048 + 0*1024 + boff1); \
    DST[2] = *(const short8*)((BBASE) + (nq)*2048 + 1*1024 + boff0); \
    DST[3] = *(const short8*)((BBASE) + (nq)*2048 + 1*1024 + boff1); \
} while (0)

#define QUAD(mq, nq, AS, BS) do { \
    acc[(mq)*4+0][(nq)*2+0] = MF(AS[0], BS[0], acc[(mq)*4+0][(nq)*2+0]); \
    acc[(mq)*4+0][(nq)*2+1] = MF(AS[0], BS[2], acc[(mq)*4+0][(nq)*2+1]); \
    acc[(mq)*4+1][(nq)*2+0] = MF(AS[2], BS[0], acc[(mq)*4+1][(nq)*2+0]); \
    acc[(mq)*4+1][(nq)*2+1] = MF(AS[2], BS[2], acc[(mq)*4+1][(nq)*2+1]); \
    acc[(mq)*4+2][(nq)*2+0] = MF(AS[4], BS[0], acc[(mq)*4+2][(nq)*2+0]); \
    acc[(mq)*4+2][(nq)*2+1] = MF(AS[4], BS[2], acc[(mq)*4+2][(nq)*2+1]); \
    acc[(mq)*4+3][(nq)*2+0] = MF(AS[6], BS[0], acc[(mq)*4+3][(nq)*2+0]); \
    acc[(mq)*4+3][(nq)*2+1] = MF(AS[6], BS[2], acc[(mq)*4+3][(nq)*2+1]); \
    acc[(mq)*4+0][(nq)*2+0] = MF(AS[1], BS[1], acc[(mq)*4+0][(nq)*2+0]); \
    acc[(mq)*4+0][(nq)*2+1] = MF(AS[1], BS[3], acc[(mq)*4+0][(nq)*2+1]); \
    acc[(mq)*4+1][(nq)*2+0] = MF(AS[3], BS[1], acc[(mq)*4+1][(nq)*2+0]); \
    acc[(mq)*4+1][(nq)*2+1] = MF(AS[3], BS[3], acc[(mq)*4+1][(nq)*2+1]); \
    acc[(mq)*4+2][(nq)*2+0] = MF(AS[5], BS[1], acc[(mq)*4+2][(nq)*2+0]); \
    acc[(mq)*4+2][(nq)*2+1] = MF(AS[5], BS[3], acc[(mq)*4+2][(nq)*2+1]); \
    acc[(mq)*4+3][(nq)*2+0] = MF(AS[7], BS[1], acc[(mq)*4+3][(nq)*2+0]); \
    acc[(mq)*4+3][(nq)*2+1] = MF(AS[7], BS[3], acc[(mq)*4+3][(nq)*2+1]); \
} while (0)

// R2/R7 ledger with the LEADING barrier of each phase removed (trailing bar + guards kept).
// Safety: wave skew < 1 phase (trailing bar); every stage overwrites a region whose last
// ds_read is >=1 full phase earlier (audited P1..P8); per-wave lgkm0 precedes trailing bar,
// so all reads drain before any wave reaches the overwriting stage. vmcnt FIFO unchanged.
// R8 (deep-flight), R10 (persistent), R13 (BK=32, acc spills) all REGRESSED — keep this.
#define GITER(t, TAIL) do { \
    /* ph1 */ \
    LDB4(Bs0, Bbase0, 0); \
    STAGE_A(1, 0, (t) + 1); \
    SB; LGKM0; SB; \
    PRIO1; QUAD(0, 0, As0, Bs0); PRIO0; SB; FBAR; \
    /* ph2 */ \
    LDB4(Bs1, Bbase0, 1); \
    STAGE_A(1, 1, (t) + 1); \
    SB; LGKM0; SB; \
    PRIO1; QUAD(0, 1, As0, Bs1); PRIO0; SB; FBAR; \
    /* ph3 */ \
    LDA8(As1, Abase0, 1); \
    if (!(TAIL)) STAGE_B(0, 0, (t) + 2); \
    SB; LGKM0; SB; \
    PRIO1; QUAD(1, 1, As1, Bs1); PRIO0; SB; \
    if (TAIL) { VMCNT(0); } else { VMCNT(2); } \
    FBAR; \
    /* ph4 */ \
    LDA8(As0, Abase1, 0); \
    if (!(TAIL)) STAGE_B(0, 1, (t) + 2); \
    SB; LGKM0; SB; \
    PRIO1; QUAD(1, 0, As1, Bs0); PRIO0; SB; FBAR; \
    /* ph5 */ \
    LDB4(Bs0, Bbase1, 0); \
    if (!(TAIL)) STAGE_A(0, 0, (t) + 2); \
    SB; LGKM0; SB; \
    PRIO1; QUAD(0, 0, As0, Bs0); PRIO0; SB; FBAR; \
    /* ph6 */ \
    LDB4(Bs1, Bbase1, 1); \
    if (!(TAIL)) STAGE_A(0, 1, (t) + 2); \
    SB; LGKM0; SB; \
    PRIO1; QUAD(0, 1, As0, Bs1); PRIO0; SB; FBAR; \
    /* ph7 */ \
    LDA8(As1, Abase1, 1); \
    if (!(TAIL)) STAGE_B(1, 0, (t) + 3); \
    SB; LGKM0; SB; \
    PRIO1; QUAD(1, 1, As1, Bs1); PRIO0; SB; \
    if (!(TAIL)) { VMCNT(2); } \
    FBAR; \
    /* ph8 */ \
    if (!(TAIL)) { LDA8(As0, Abase0, 0); STAGE_B(1, 1, (t) + 3); } \
    SB; LGKM0; SB; \
    PRIO1; QUAD(1, 0, As1, Bs0); PRIO0; SB; FBAR; \
} while (0)

__global__ __launch_bounds__(512, 2) void gemm256(const u16* __restrict__ Abuf,
                                                  const u16* __restrict__ Bbuf,
                                                  const float* __restrict__ wT,
                                                  const float* __restrict__ b_strat,
                                                  float* __restrict__ out) {
    __shared__ __align__(16) u16 lds[2][4][8192]; // 128 KiB

    const int tid = threadIdx.x;
    const int lane = tid & 63;
    const int wv = tid >> 6;
    const int wr = wv >> 2;      // 0..1 (M)
    const int wc = wv & 3;       // 0..3 (N)
    const int fr = lane & 15;
    const int fq = lane >> 4;

    // XCD-aware bijective mapping, m-fastest within XCD (R9): FETCH 76.5->52.4 MB measured.
    const int bid = blockIdx.x;
    const int xcd = bid & 7;
    const int k = bid >> 3;                  // 0..63
    const int m0 = (xcd * 4 + (k & 3)) * 256;
    const int n0 = (k >> 2) * 256;

    // staging: per-thread linear LDS slot -> pre-swizzled global source
    const int s_r = tid >> 3;                               // row in half (0..63), +64 for 2nd load
    const int s_c = ((tid & 7) * 8) ^ ((s_r & 7) << 3);     // elem col, inverse-swizzled
    const u16* agA = Abuf + (size_t)(m0 + s_r) * 1024 + s_c;
    const u16* agB = Bbuf + (size_t)(n0 + s_r) * 1024 + s_c;

    // frag-read offsets (u16 units) within a 128x64 region, row stride 64 u16
    const int aoff0 = fr * 64 + ((fq ^ (fr & 7)) * 8);
    const int aoff1 = fr * 64 + (((fq + 4) ^ (fr & 7)) * 8);
    const int bof = (wc & 1) * 4096;
    const int boff0 = bof + aoff0;
    const int boff1 = bof + aoff1;

    const u16* Abase0 = (const u16*)&lds[0][wr][0];
    const u16* Abase1 = (const u16*)&lds[1][wr][0];
    const u16* Bbase0 = (const u16*)&lds[0][2 + (wc >> 1)][0];
    const u16* Bbase1 = (const u16*)&lds[1][2 + (wc >> 1)][0];

    f32x4 acc[8][4] = {};
    short8 As0[8], As1[8], Bs0[4], Bs1[4];

    // prologue: kt0 full into buf0, B(kt1) into buf1, then force kt0, pre-read A(kt0)m0
    STAGE_A(0, 0, 0); STAGE_A(0, 1, 0); STAGE_B(0, 0, 0); STAGE_B(0, 1, 0);
    STAGE_B(1, 0, 1); STAGE_B(1, 1, 1);
    SB; VMCNT(4); FBAR;
    LDA8(As0, Abase0, 0);

#pragma unroll 1
    for (int t = 0; t < 14; t += 2) { GITER(t, 0); }
    GITER(14, 1);

    // ---- block-local weighted combine epilogue (DPP row-sum + vectorized wT loads) ----
    // C layout: row = crow + im*16 + q, col' = n0 + wc*64 + jn*16 + fr  (m89-verified)
    // col' = a*32 + e  ->  e = (jn&1)*16 + fr,  a = (n0>>5) + wc*2 + (jn>>1)
    const int crow = m0 + wr * 128 + fq * 4;
    const int a0 = (n0 >> 5) + wc * 2;
    const float bs00 = b_strat[fr * 128 + a0];
    const float bs10 = b_strat[(16 + fr) * 128 + a0];
    const float bs01 = b_strat[fr * 128 + a0 + 1];
    const float bs11 = b_strat[(16 + fr) * 128 + a0 + 1];
    const float* wt0 = wT + (size_t)fr * Bq;
    const float* wt1 = wT + (size_t)(16 + fr) * Bq;
#pragma unroll
    for (int im = 0; im < 8; ++im) {
        f32x4 w0 = *(const f32x4*)(wt0 + crow + im * 16);   // w[fr][row] for q=0..3
        f32x4 w1 = *(const f32x4*)(wt1 + crow + im * 16);
#pragma unroll
        for (int q = 0; q < 4; ++q) {
            float v0 = w0[q] * (acc[im][0][q] + bs00) + w1[q] * (acc[im][1][q] + bs10);
            float v1 = w0[q] * (acc[im][2][q] + bs01) + w1[q] * (acc[im][3][q] + bs11);
            v0 = red16(v0);
            v1 = red16(v1);
            if (fr == 0) {
                const int row = crow + im * 16 + q;
                out[(size_t)row * 128 + a0] = v0;
                out[(size_t)row * 128 + a0 + 1] = v1;
            }
        }
    }
}

extern "C" void kernel_launch(void* const* d_in, const int* in_sizes, int n_in,
                              void* d_out, int out_size, void* d_ws, size_t ws_size,
                              hipStream_t stream) {
    (void)in_sizes; (void)n_in; (void)out_size; (void)ws_size;
    const float* x       = (const float*)d_in[0];
    const float* W_att   = (const float*)d_in[1];
    const float* b_att   = (const float*)d_in[2];
    const float* abias   = (const float*)d_in[3];
    const float* W_strat = (const float*)d_in[4];
    const float* b_strat = (const float*)d_in[5];
    const float* gu      = (const float*)d_in[6];
    float* out = (float*)d_out;

    // ws layout: xb [8192][1024] | Wb [4096][1024] (permuted, contiguous bf16) | wT [32][8192] f32
    u16* xb = (u16*)d_ws;
    u16* Wb = xb + (size_t)Bq * Dq;
    float* wT = (float*)(Wb + (size_t)NSTRAT * Dq);

    cvt_fused<<<(Bq * Dq + NSTRAT * Dq) / (256 * 8), 256, 0, stream>>>(x, W_strat, xb);

    logits_kernel<<<Bq / 128, 512, 0, stream>>>(xb, W_att, b_att, abias, gu, wT);

    gemm256<<<512, 512, 0, stream>>>(xb, Wb, wT, b_strat, out);
}